// Round 5
// baseline (2996.625 us; speedup 1.0000x reference)
//
#include <hip/hip_runtime.h>
#include <hip/hip_bf16.h>
#include <cstdint>
#include <cstddef>

// B=16, S=128, IN=200, H=256, 4H=1024, 2H=512

typedef __attribute__((ext_vector_type(8))) short bf16x8;
typedef __attribute__((ext_vector_type(4))) float f32x4;

__device__ __forceinline__ float bf2f(unsigned short u) {
    return __uint_as_float(((unsigned)u) << 16);
}
__device__ __forceinline__ unsigned short f2bf(float f) {
    unsigned u = __float_as_uint(f);
    u = (u + 0x7FFFu + ((u >> 16) & 1u)) >> 16;
    return (unsigned short)u;
}

// LDS-only barrier: wait ds ops, raw s_barrier, no vmcnt drain (global ops stay in flight)
__device__ __forceinline__ void lds_sync() {
    asm volatile("s_waitcnt lgkmcnt(0)" ::: "memory");
    __builtin_amdgcn_s_barrier();
    __builtin_amdgcn_sched_barrier(0);
}

// ---------------- prep kernels ----------------

// dst[z][k][n] = src[z][n][k], n<1024, k<K
__global__ void k_transpose_N1024(const float* __restrict__ src, float* __restrict__ dst, int K) {
    int z = blockIdx.z;
    int idx = blockIdx.x * 256 + threadIdx.x;
    if (idx >= K * 1024) return;
    int k = idx >> 10, n = idx & 1023;
    dst[(size_t)z * K * 1024 + idx] = src[(size_t)z * 1024 * K + (size_t)n * K + k];
}

// Whh (2,1024,256) fp32 -> A-fragment layout bf16:
// Wfrag[((d*16+w)*8+ks)*4+t][l][e] = bf16(Whh[d][(r&3)*256 + w*16 + t*4 + (r>>2)][ks*32+(l>>4)*8+e]), r=l&15
__global__ void k_wfrag(const float* __restrict__ Whh, unsigned short* __restrict__ Wfrag) {
    int idx = blockIdx.x * 256 + threadIdx.x;   // 65536 total
    int l = idx & 63;
    int t = (idx >> 6) & 3;
    int ks = (idx >> 8) & 7;
    int w = (idx >> 11) & 15;
    int d = idx >> 15;
    int r = l & 15;
    int kbase = ks * 32 + (l >> 4) * 8;
    int row = (r & 3) * 256 + w * 16 + t * 4 + (r >> 2);
    const float* src = Whh + (size_t)d * (1024 * 256) + (size_t)row * 256 + kbase;
    unsigned short* dst = Wfrag + (size_t)idx * 8;
#pragma unroll
    for (int e = 0; e < 8; ++e) dst[e] = f2bf(src[e]);
}

// W1 (256,1024) -> dst[k][o], k<512, o<512
__global__ void k_w1t(const float* __restrict__ W1, float* __restrict__ dst) {
    int idx = blockIdx.x * 256 + threadIdx.x;
    if (idx >= 512 * 512) return;
    int k = idx >> 9, o = idx & 511;
    dst[idx] = (o < 256) ? W1[(size_t)o * 1024 + k] : W1[(size_t)(o - 256) * 1024 + 512 + k];
}

__global__ void k_bias(const float* __restrict__ bih0, const float* __restrict__ bhh0,
                       const float* __restrict__ bih1, const float* __restrict__ bhh1,
                       const float* __restrict__ b1,
                       float* __restrict__ bsum0, float* __restrict__ bsum1, float* __restrict__ bhab) {
    int idx = blockIdx.x * 256 + threadIdx.x;
    if (idx < 2048) bsum0[idx] = bih0[idx] + bhh0[idx];
    else if (idx < 4096) { int i = idx - 2048; bsum1[i] = bih1[i] + bhh1[i]; }
    else if (idx < 4608) { int i = idx - 4096; bhab[i] = (i < 256) ? b1[i] : 0.f; }
}

// xg[d][b*128+t][n] -> xgfrag: float at d*2097152 + (t*4096 + (j>>4)*256 + ((j>>2)&3)*64 + (j&3)*16 + b)*4 + q
// where n = q*256 + j
__global__ __launch_bounds__(256) void k_reorder(const float* __restrict__ xg, float* __restrict__ xgf) {
    int idx = blockIdx.x * 256 + threadIdx.x;   // 1048576 total
    int n4 = idx & 255;
    int m = (idx >> 8) & 2047;
    int d = idx >> 19;
    int n0 = n4 * 4;
    int q = n0 >> 8;
    int jbase = n0 & 255;
    int b = m >> 7, t = m & 127;
    float4 v = *(const float4*)(xg + ((size_t)(d * 2048 + m)) * 1024 + n0);
    float* base = xgf + (size_t)d * 2097152;
    float vv[4] = {v.x, v.y, v.z, v.w};
#pragma unroll
    for (int dj = 0; dj < 4; ++dj) {
        int j = jbase + dj;
        int fi = (t * 4096 + (j >> 4) * 256 + ((j >> 2) & 3) * 64 + dj * 16 + b) * 4 + q;
        base[fi] = vv[dj];
    }
}

// ---------------- generic GEMM: out[z][m][n] = bias[z][n] + sum_k A[m][k]*Wt[z][k][n] ----------------
template<typename AT>
__global__ __launch_bounds__(256) void k_gemm(
    const AT* __restrict__ A, const float* __restrict__ Wt,
    const float* __restrict__ bias, float* __restrict__ out,
    int M, int K, int N)
{
    int z = blockIdx.z;
    const float* Wtz = Wt + (size_t)z * K * N;
    float* outz = out + (size_t)z * M * N;
    const float* biasz = bias + (size_t)z * N;

    __shared__ float As[16 * 512];
    int tid = threadIdx.x;
    int mq = tid >> 6;
    int nq = tid & 63;
    int n0 = blockIdx.x * 256 + nq * 4;
    int mbase = blockIdx.y * 16;

    for (int r = 0; r < 16; ++r) {
        const AT* Ar = A + (size_t)(mbase + r) * K;
        for (int c = tid; c < K; c += 256) {
            if constexpr (sizeof(AT) == 2) As[r * K + c] = bf2f((unsigned short)Ar[c]);
            else As[r * K + c] = (float)Ar[c];
        }
    }
    __syncthreads();

    float4 bv = *(const float4*)(biasz + n0);
    float acc[4][4];
#pragma unroll
    for (int mi = 0; mi < 4; mi++) { acc[mi][0] = bv.x; acc[mi][1] = bv.y; acc[mi][2] = bv.z; acc[mi][3] = bv.w; }

    const float* asr = As + (mq * 4) * K;
    for (int k = 0; k < K; ++k) {
        float4 w = *(const float4*)(Wtz + (size_t)k * N + n0);
        float x0 = asr[k];
        float x1 = asr[K + k];
        float x2 = asr[2 * K + k];
        float x3 = asr[3 * K + k];
        acc[0][0] += x0 * w.x; acc[0][1] += x0 * w.y; acc[0][2] += x0 * w.z; acc[0][3] += x0 * w.w;
        acc[1][0] += x1 * w.x; acc[1][1] += x1 * w.y; acc[1][2] += x1 * w.z; acc[1][3] += x1 * w.w;
        acc[2][0] += x2 * w.x; acc[2][1] += x2 * w.y; acc[2][2] += x2 * w.z; acc[2][3] += x2 * w.w;
        acc[3][0] += x3 * w.x; acc[3][1] += x3 * w.y; acc[3][2] += x3 * w.z; acc[3][3] += x3 * w.w;
    }
#pragma unroll
    for (int mi = 0; mi < 4; mi++) {
        size_t m = (size_t)mbase + mq * 4 + mi;
        *(float4*)(outz + m * N + n0) = make_float4(acc[mi][0], acc[mi][1], acc[mi][2], acc[mi][3]);
    }
}

// ---------------- MFMA LSTM recurrence: one block per direction ----------------
#define GATE(A, C, H) { \
    float gi = A[0], gf = A[1], gg = A[2], go = A[3]; \
    float si = __builtin_amdgcn_rcpf(1.f + __expf(-gi)); \
    float sf = __builtin_amdgcn_rcpf(1.f + __expf(-gf)); \
    float so = __builtin_amdgcn_rcpf(1.f + __expf(-go)); \
    float eg = __expf(2.f * gg); \
    float tg = 1.f - 2.f * __builtin_amdgcn_rcpf(eg + 1.f); \
    C = sf * C + si * tg; \
    float ec = __expf(2.f * C); \
    float tc = 1.f - 2.f * __builtin_amdgcn_rcpf(ec + 1.f); \
    H = so * tc; }

// hB layout (per buffer, u16 units): idx = (k>>3)*128 + b*8 + (k&7)
// E staging (per buffer, u16 units): idx = b*2120 + ts*264 + k   (k<256, ts<8, b<16)
__global__ __launch_bounds__(1024) void k_lstm_mfma(
    const float* __restrict__ xgf,            // [2][128][16][4][64][4]
    const unsigned short* __restrict__ Wfrag, // [2][16][8][4][64][8] bf16
    unsigned short* __restrict__ emb)         // [2048][512] bf16; this dir writes cols d*256..
{
    const int d = blockIdx.x;
    const int tid = threadIdx.x;
    const int w = tid >> 6;
    const int l = tid & 63;
    const int b = l & 15;
    const int jh = l >> 4;

    __shared__ __align__(16) unsigned short hB[2][4096];   // 16 KiB
    __shared__ __align__(16) unsigned short E[2][33920];   // 132.5 KiB staging

    // all weights register-resident: 32 bf16x8 = 128 regs
    const unsigned short* wgp = Wfrag + ((size_t)(d * 16 + w)) * (8 * 4 * 64 * 8);
    bf16x8 Wr[8][4];
#pragma unroll
    for (int ks = 0; ks < 8; ++ks)
#pragma unroll
        for (int t4 = 0; t4 < 4; ++t4)
            Wr[ks][t4] = *(const bf16x8*)(wgp + ((ks * 4 + t4) * 64 + l) * 8);

    // zero both h buffers
    {
        uint64_t* z = (uint64_t*)&hB[0][0];
        z[tid] = 0ull;
        z[tid + 1024] = 0ull;
    }

    const int sgn = d ? -1 : 1;
    const f32x4* xb = (const f32x4*)(xgf) + (size_t)d * 524288;
    const int xo = w * 256 + l;

    // prologue: acc = xg(t(0)), q = xg(t(1))
    int t = d ? 127 : 0;
    f32x4 a0 = xb[t * 4096 + xo];
    f32x4 a1 = xb[t * 4096 + xo + 64];
    f32x4 a2 = xb[t * 4096 + xo + 128];
    f32x4 a3 = xb[t * 4096 + xo + 192];
    int t1 = t + sgn;
    f32x4 q0 = xb[t1 * 4096 + xo];
    f32x4 q1 = xb[t1 * 4096 + xo + 64];
    f32x4 q2 = xb[t1 * 4096 + xo + 128];
    f32x4 q3 = xb[t1 * 4096 + xo + 192];

    float c0 = 0.f, c1 = 0.f, c2 = 0.f, c3 = 0.f;
    const int hrd = jh * 128 + b * 8;          // + ks*512 (u16)
    const int hwoff = w * 256 + b * 8 + jh;    // hB writes at +0,+4,+128,+132
    const int ewoff = b * 2120 + w * 16 + jh;  // E writes at + ts*264 + t4*4
    // flush mapping: tid -> (fb, fts, fq)
    const int fq = tid & 7;
    const int fts = (tid >> 3) & 7;
    const int fb = tid >> 6;
    const int frd = fb * 2120 + fts * 264 + fq * 32;            // E read base (u16)
    unsigned short* fst = emb + (size_t)fb * 128 * 512 + d * 256 + fq * 32;
    __syncthreads();

    int cur = 0, ebuf = 0;
    for (int s = 0; s < 128; ++s) {
        const int ts = s & 7;
        // issue prefetch for t(s+2) FIRST (depth-2 pipeline)
        int sp2 = s + 2; if (sp2 > 127) sp2 = 127;
        const int tp = d ? (127 - sp2) : sp2;
        f32x4 n0 = xb[tp * 4096 + xo];
        f32x4 n1 = xb[tp * 4096 + xo + 64];
        f32x4 n2 = xb[tp * 4096 + xo + 128];
        f32x4 n3 = xb[tp * 4096 + xo + 192];

        // MFMA: split K-chain 4+4 to halve dependent-MFMA depth
        const unsigned short* hbuf = &hB[cur][0];
        f32x4 z0 = {0.f, 0.f, 0.f, 0.f}, z1 = z0, z2 = z0, z3 = z0;
#pragma unroll
        for (int ks = 0; ks < 4; ++ks) {
            bf16x8 hf = *(const bf16x8*)(hbuf + ks * 512 + hrd);
            a0 = __builtin_amdgcn_mfma_f32_16x16x32_bf16(Wr[ks][0], hf, a0, 0, 0, 0);
            a1 = __builtin_amdgcn_mfma_f32_16x16x32_bf16(Wr[ks][1], hf, a1, 0, 0, 0);
            a2 = __builtin_amdgcn_mfma_f32_16x16x32_bf16(Wr[ks][2], hf, a2, 0, 0, 0);
            a3 = __builtin_amdgcn_mfma_f32_16x16x32_bf16(Wr[ks][3], hf, a3, 0, 0, 0);
        }
#pragma unroll
        for (int ks = 4; ks < 8; ++ks) {
            bf16x8 hf = *(const bf16x8*)(hbuf + ks * 512 + hrd);
            z0 = __builtin_amdgcn_mfma_f32_16x16x32_bf16(Wr[ks][0], hf, z0, 0, 0, 0);
            z1 = __builtin_amdgcn_mfma_f32_16x16x32_bf16(Wr[ks][1], hf, z1, 0, 0, 0);
            z2 = __builtin_amdgcn_mfma_f32_16x16x32_bf16(Wr[ks][2], hf, z2, 0, 0, 0);
            z3 = __builtin_amdgcn_mfma_f32_16x16x32_bf16(Wr[ks][3], hf, z3, 0, 0, 0);
        }
        a0 = a0 + z0; a1 = a1 + z1; a2 = a2 + z2; a3 = a3 + z3;

        float h0, h1, h2, h3;
        GATE(a0, c0, h0);
        GATE(a1, c1, h1);
        GATE(a2, c2, h2);
        GATE(a3, c3, h3);
        unsigned short u0 = f2bf(h0), u1 = f2bf(h1), u2 = f2bf(h2), u3 = f2bf(h3);

        // stage h into E (LDS, ≤2-way banks) instead of scattered global stores
        {
            unsigned short* ep = &E[ebuf][ewoff + ts * 264];
            ep[0] = u0; ep[4] = u1; ep[8] = u2; ep[12] = u3;
        }
        // h exchange into the other buffer
        {
            unsigned short* hn = &hB[cur ^ 1][0];
            hn[hwoff] = u0;
            hn[hwoff + 4] = u1;
            hn[hwoff + 128] = u2;
            hn[hwoff + 132] = u3;
        }
        lds_sync();   // lgkmcnt(0) + s_barrier; vm ops stay in flight

        // coalesced flush of 8 staged steps, once per 8 steps
        if (ts == 7) {
            const unsigned short* er = &E[ebuf][frd];
            bf16x8 v0 = *(const bf16x8*)(er);
            bf16x8 v1 = *(const bf16x8*)(er + 8);
            bf16x8 v2 = *(const bf16x8*)(er + 16);
            bf16x8 v3 = *(const bf16x8*)(er + 24);
            const int trow = t - (7 - fts) * sgn;
            unsigned short* dst = fst + (size_t)trow * 512;
            *(bf16x8*)(dst) = v0;
            *(bf16x8*)(dst + 8) = v1;
            *(bf16x8*)(dst + 16) = v2;
            *(bf16x8*)(dst + 24) = v3;
            ebuf ^= 1;
        }

        // rotate pipeline
        a0 = q0; a1 = q1; a2 = q2; a3 = q3;
        q0 = n0; q1 = n1; q2 = n2; q3 = n3;
        cur ^= 1;
        t += sgn;
    }
}

// ---------------- fused pairwise scorer ----------------
__global__ __launch_bounds__(256) void k_scorer(
    const float* __restrict__ HaHb, const float* __restrict__ W2,
    const float* __restrict__ b2, const float* __restrict__ W3,
    const float* __restrict__ b3v, float* __restrict__ score)
{
    int jt = blockIdx.x;
    int i  = blockIdx.y;
    int b  = blockIdx.z;
    int tid = threadIdx.x;

    __shared__ __align__(16) float ha[256];
    __shared__ __align__(16) float h1[32 * 260];
    __shared__ __align__(16) float w2s[128 * 36];

    ha[tid] = HaHb[(size_t)(b * 128 + i) * 512 + tid];
    __syncthreads();

    {
        int j = tid >> 3;
        int q = tid & 7;
        const float* hbrow = HaHb + (size_t)(b * 128 + jt * 32 + j) * 512 + 256;
        float* h1r = h1 + j * 260;
#pragma unroll
        for (int cc = 0; cc < 32; ++cc) {
            int c = q + cc * 8;
            float v = ha[c] + hbrow[c];
            h1r[c] = v > 0.f ? v : 0.f;
        }
    }

    float acc[4][4] = {};
    int jq = tid >> 5;
    int rq = tid & 31;

    for (int ch = 0; ch < 8; ++ch) {
        int cb = ch * 32;
        __syncthreads();
        for (int idx = tid; idx < 128 * 32; idx += 256) {
            int r = idx >> 5, cc = idx & 31;
            w2s[r * 36 + cc] = W2[(size_t)r * 256 + cb + cc];
        }
        __syncthreads();
#pragma unroll
        for (int cc = 0; cc < 32; cc += 4) {
            float4 hv[4], wv[4];
#pragma unroll
            for (int jj = 0; jj < 4; ++jj)
                hv[jj] = *(const float4*)(h1 + (jq + jj * 8) * 260 + cb + cc);
#pragma unroll
            for (int rr = 0; rr < 4; ++rr)
                wv[rr] = *(const float4*)(w2s + (rq + rr * 32) * 36 + cc);
#pragma unroll
            for (int jj = 0; jj < 4; ++jj)
#pragma unroll
                for (int rr = 0; rr < 4; ++rr)
                    acc[jj][rr] += hv[jj].x * wv[rr].x + hv[jj].y * wv[rr].y +
                                   hv[jj].z * wv[rr].z + hv[jj].w * wv[rr].w;
        }
    }

    float part0 = 0.f, part1 = 0.f, part2 = 0.f, part3 = 0.f;
#pragma unroll
    for (int rr = 0; rr < 4; ++rr) {
        int r = rq + rr * 32;
        float bb = b2[r], ww = W3[r];
        float t0 = acc[0][rr] + bb; if (t0 > 0.f) part0 += t0 * ww;
        float t1 = acc[1][rr] + bb; if (t1 > 0.f) part1 += t1 * ww;
        float t2 = acc[2][rr] + bb; if (t2 > 0.f) part2 += t2 * ww;
        float t3 = acc[3][rr] + bb; if (t3 > 0.f) part3 += t3 * ww;
    }
#pragma unroll
    for (int off = 16; off >= 1; off >>= 1) {
        part0 += __shfl_xor(part0, off, 32);
        part1 += __shfl_xor(part1, off, 32);
        part2 += __shfl_xor(part2, off, 32);
        part3 += __shfl_xor(part3, off, 32);
    }
    if (rq == 0) {
        float bb3 = b3v[0];
        float p[4] = {part0, part1, part2, part3};
#pragma unroll
        for (int jj = 0; jj < 4; ++jj) {
            int jg = jt * 32 + jq + jj * 8;
            float sc = p[jj] + bb3;
            sc = sc > 0.f ? sc : 0.f;
            if (jg == i || jg == 0) sc = 0.f;
            score[(size_t)(b * 128 + i) * 128 + jg] = sc;
        }
    }
}

// ---------------- loss ----------------
__global__ __launch_bounds__(128) void k_loss1(
    const float* __restrict__ score, const int* __restrict__ tree, float* __restrict__ res)
{
    int k = blockIdx.x;
    int b = blockIdx.y;
    int head = tree[((size_t)b * 128 + k + 1) * 2 + 0];
    int dep  = tree[((size_t)b * 128 + k + 1) * 2 + 1];
    int i = threadIdx.x;
    float s = score[((size_t)b * 128 + i) * 128 + dep];
    float v = (i == dep) ? 0.f : __expf(s);
    __shared__ float redu[2];
#pragma unroll
    for (int off = 32; off >= 1; off >>= 1) v += __shfl_down(v, off, 64);
    if ((i & 63) == 0) redu[i >> 6] = v;
    __syncthreads();
    if (i == 0) {
        float norm = redu[0] + redu[1];
        float num = score[((size_t)b * 128 + head) * 128 + dep];
        res[b * 127 + k] = __logf(norm) - num;
    }
}

__global__ __launch_bounds__(256) void k_loss2(const float* __restrict__ res, float* __restrict__ out) {
    int tid = threadIdx.x;
    float a = 0.f;
    for (int idx = tid; idx < 16 * 127; idx += 256) a += res[idx];
    __shared__ float sm[256];
    sm[tid] = a;
    __syncthreads();
    for (int off = 128; off >= 1; off >>= 1) {
        if (tid < off) sm[tid] += sm[tid + off];
        __syncthreads();
    }
    if (tid == 0) out[0] = sm[0] / 127.f;
}

// ---------------- host launcher ----------------
extern "C" void kernel_launch(void* const* d_in, const int* in_sizes, int n_in,
                              void* d_out, int out_size, void* d_ws, size_t ws_size,
                              hipStream_t stream) {
    (void)in_sizes; (void)n_in; (void)out_size; (void)ws_size;
    const float* X    = (const float*)d_in[0];
    const float* Wih0 = (const float*)d_in[1];
    const float* Whh0 = (const float*)d_in[2];
    const float* bih0 = (const float*)d_in[3];
    const float* bhh0 = (const float*)d_in[4];
    const float* Wih1 = (const float*)d_in[5];
    const float* Whh1 = (const float*)d_in[6];
    const float* bih1 = (const float*)d_in[7];
    const float* bhh1 = (const float*)d_in[8];
    const float* W1   = (const float*)d_in[9];
    const float* b1   = (const float*)d_in[10];
    const float* W2   = (const float*)d_in[11];
    const float* b2   = (const float*)d_in[12];
    const float* W3   = (const float*)d_in[13];
    const float* b3   = (const float*)d_in[14];
    const int*   tree = (const int*)d_in[15];
    float* out = (float*)d_out;   // [0]=loss, [1..]=score

    float* ws = (float*)d_ws;
    size_t o = 0;
    float* WihT0 = ws + o; o += (size_t)2 * 200 * 1024;
    float* WihT1 = ws + o; o += (size_t)2 * 512 * 1024;
    float* W1T   = ws + o; o += (size_t)512 * 512;
    float* bsum0 = ws + o; o += 2048;
    float* bsum1 = ws + o; o += 2048;
    float* bhab  = ws + o; o += 512;
    unsigned short* Wf0 = (unsigned short*)(ws + o); o += (size_t)2 * 16 * 8 * 4 * 64 * 8 / 2;
    unsigned short* Wf1 = (unsigned short*)(ws + o); o += (size_t)2 * 16 * 8 * 4 * 64 * 8 / 2;
    float* xg   = ws + o; o += (size_t)2 * 2048 * 1024;   // shared between layers
    float* xgf  = ws + o; o += (size_t)2 * 2048 * 1024;   // shared between layers
    unsigned short* emb0 = (unsigned short*)(ws + o); o += (size_t)2048 * 512 / 2;
    unsigned short* emb1 = (unsigned short*)(ws + o); o += (size_t)2048 * 512 / 2;
    float* HaHb = ws + o; o += (size_t)2048 * 512;
    float* res  = ws + o; o += 2048;

    // prep
    k_transpose_N1024<<<dim3(800, 1, 2), 256, 0, stream>>>(Wih0, WihT0, 200);
    k_transpose_N1024<<<dim3(2048, 1, 2), 256, 0, stream>>>(Wih1, WihT1, 512);
    k_wfrag<<<256, 256, 0, stream>>>(Whh0, Wf0);
    k_wfrag<<<256, 256, 0, stream>>>(Whh1, Wf1);
    k_w1t<<<1024, 256, 0, stream>>>(W1, W1T);
    k_bias<<<18, 256, 0, stream>>>(bih0, bhh0, bih1, bhh1, b1, bsum0, bsum1, bhab);

    // layer 0
    k_gemm<float><<<dim3(4, 128, 2), 256, 0, stream>>>(X, WihT0, bsum0, xg, 2048, 200, 1024);
    k_reorder<<<4096, 256, 0, stream>>>(xg, xgf);
    k_lstm_mfma<<<2, 1024, 0, stream>>>(xgf, Wf0, emb0);
    // layer 1
    k_gemm<unsigned short><<<dim3(4, 128, 2), 256, 0, stream>>>(emb0, WihT1, bsum1, xg, 2048, 512, 1024);
    k_reorder<<<4096, 256, 0, stream>>>(xg, xgf);
    k_lstm_mfma<<<2, 1024, 0, stream>>>(xgf, Wf1, emb1);
    // Ha|Hb
    k_gemm<unsigned short><<<dim3(2, 128, 1), 256, 0, stream>>>(emb1, W1T, bhab, HaHb, 2048, 512, 512);
    // scorer -> out+1
    k_scorer<<<dim3(4, 128, 16), 256, 0, stream>>>(HaHb, W2, b2, W3, b3, out + 1);
    // loss
    k_loss1<<<dim3(127, 16), 128, 0, stream>>>(out + 1, tree, res);
    k_loss2<<<1, 256, 0, stream>>>(res, out);
}

// Round 6
// 1309.289 us; speedup vs baseline: 2.2887x; 2.2887x over previous
//
#include <hip/hip_runtime.h>
#include <hip/hip_bf16.h>
#include <cstdint>
#include <cstddef>

// B=16, S=128, IN=200, H=256, 4H=1024, 2H=512

typedef __attribute__((ext_vector_type(8))) short bf16x8;
typedef __attribute__((ext_vector_type(4))) float f32x4;

__device__ __forceinline__ float bf2f(unsigned short u) {
    return __uint_as_float(((unsigned)u) << 16);
}
__device__ __forceinline__ unsigned short f2bf(float f) {
    unsigned u = __float_as_uint(f);
    u = (u + 0x7FFFu + ((u >> 16) & 1u)) >> 16;
    return (unsigned short)u;
}

// ---------------- prep kernels ----------------

// dst[z][k][n] = src[z][n][k], n<1024, k<K
__global__ void k_transpose_N1024(const float* __restrict__ src, float* __restrict__ dst, int K) {
    int z = blockIdx.z;
    int idx = blockIdx.x * 256 + threadIdx.x;
    if (idx >= K * 1024) return;
    int k = idx >> 10, n = idx & 1023;
    dst[(size_t)z * K * 1024 + idx] = src[(size_t)z * 1024 * K + (size_t)n * K + k];
}

// Whh (2,1024,256) fp32 -> A-fragment layout bf16:
// Wfrag[((d*16+w)*8+ks)*4+t][l][e] = bf16(Whh[d][(r&3)*256 + w*16 + t*4 + (r>>2)][ks*32+(l>>4)*8+e]), r=l&15
__global__ void k_wfrag(const float* __restrict__ Whh, unsigned short* __restrict__ Wfrag) {
    int idx = blockIdx.x * 256 + threadIdx.x;   // 65536 total
    int l = idx & 63;
    int t = (idx >> 6) & 3;
    int ks = (idx >> 8) & 7;
    int w = (idx >> 11) & 15;
    int d = idx >> 15;
    int r = l & 15;
    int kbase = ks * 32 + (l >> 4) * 8;
    int row = (r & 3) * 256 + w * 16 + t * 4 + (r >> 2);
    const float* src = Whh + (size_t)d * (1024 * 256) + (size_t)row * 256 + kbase;
    unsigned short* dst = Wfrag + (size_t)idx * 8;
#pragma unroll
    for (int e = 0; e < 8; ++e) dst[e] = f2bf(src[e]);
}

// W1 (256,1024) -> dst[k][o], k<512, o<512
__global__ void k_w1t(const float* __restrict__ W1, float* __restrict__ dst) {
    int idx = blockIdx.x * 256 + threadIdx.x;
    if (idx >= 512 * 512) return;
    int k = idx >> 9, o = idx & 511;
    dst[idx] = (o < 256) ? W1[(size_t)o * 1024 + k] : W1[(size_t)(o - 256) * 1024 + 512 + k];
}

__global__ void k_bias(const float* __restrict__ bih0, const float* __restrict__ bhh0,
                       const float* __restrict__ bih1, const float* __restrict__ bhh1,
                       const float* __restrict__ b1,
                       float* __restrict__ bsum0, float* __restrict__ bsum1, float* __restrict__ bhab) {
    int idx = blockIdx.x * 256 + threadIdx.x;
    if (idx < 2048) bsum0[idx] = bih0[idx] + bhh0[idx];
    else if (idx < 4096) { int i = idx - 2048; bsum1[i] = bih1[i] + bhh1[i]; }
    else if (idx < 4608) { int i = idx - 4096; bhab[i] = (i < 256) ? b1[i] : 0.f; }
}

// xg[d][b*128+t][n] -> xgfrag: float at d*2097152 + (t*4096 + (j>>4)*256 + ((j>>2)&3)*64 + (j&3)*16 + b)*4 + q
// where n = q*256 + j
__global__ __launch_bounds__(256) void k_reorder(const float* __restrict__ xg, float* __restrict__ xgf) {
    int idx = blockIdx.x * 256 + threadIdx.x;   // 1048576 total
    int n4 = idx & 255;
    int m = (idx >> 8) & 2047;
    int d = idx >> 19;
    int n0 = n4 * 4;
    int q = n0 >> 8;
    int jbase = n0 & 255;
    int b = m >> 7, t = m & 127;
    float4 v = *(const float4*)(xg + ((size_t)(d * 2048 + m)) * 1024 + n0);
    float* base = xgf + (size_t)d * 2097152;
    float vv[4] = {v.x, v.y, v.z, v.w};
#pragma unroll
    for (int dj = 0; dj < 4; ++dj) {
        int j = jbase + dj;
        int fi = (t * 4096 + (j >> 4) * 256 + ((j >> 2) & 3) * 64 + dj * 16 + b) * 4 + q;
        base[fi] = vv[dj];
    }
}

// ---------------- generic GEMM: out[z][m][n] = bias[z][n] + sum_k A[m][k]*Wt[z][k][n] ----------------
// A row-major fp32
__global__ __launch_bounds__(256) void k_gemm(
    const float* __restrict__ A, const float* __restrict__ Wt,
    const float* __restrict__ bias, float* __restrict__ out,
    int M, int K, int N)
{
    int z = blockIdx.z;
    const float* Wtz = Wt + (size_t)z * K * N;
    float* outz = out + (size_t)z * M * N;
    const float* biasz = bias + (size_t)z * N;

    __shared__ float As[16 * 512];
    int tid = threadIdx.x;
    int mq = tid >> 6;
    int nq = tid & 63;
    int n0 = blockIdx.x * 256 + nq * 4;
    int mbase = blockIdx.y * 16;

    for (int r = 0; r < 16; ++r) {
        const float* Ar = A + (size_t)(mbase + r) * K;
        for (int c = tid; c < K; c += 256) As[r * K + c] = Ar[c];
    }
    __syncthreads();

    float4 bv = *(const float4*)(biasz + n0);
    float acc[4][4];
#pragma unroll
    for (int mi = 0; mi < 4; mi++) { acc[mi][0] = bv.x; acc[mi][1] = bv.y; acc[mi][2] = bv.z; acc[mi][3] = bv.w; }

    const float* asr = As + (mq * 4) * K;
    for (int k = 0; k < K; ++k) {
        float4 w = *(const float4*)(Wtz + (size_t)k * N + n0);
        float x0 = asr[k];
        float x1 = asr[K + k];
        float x2 = asr[2 * K + k];
        float x3 = asr[3 * K + k];
        acc[0][0] += x0 * w.x; acc[0][1] += x0 * w.y; acc[0][2] += x0 * w.z; acc[0][3] += x0 * w.w;
        acc[1][0] += x1 * w.x; acc[1][1] += x1 * w.y; acc[1][2] += x1 * w.z; acc[1][3] += x1 * w.w;
        acc[2][0] += x2 * w.x; acc[2][1] += x2 * w.y; acc[2][2] += x2 * w.z; acc[2][3] += x2 * w.w;
        acc[3][0] += x3 * w.x; acc[3][1] += x3 * w.y; acc[3][2] += x3 * w.z; acc[3][3] += x3 * w.w;
    }
#pragma unroll
    for (int mi = 0; mi < 4; mi++) {
        size_t m = (size_t)mbase + mq * 4 + mi;
        *(float4*)(outz + m * N + n0) = make_float4(acc[mi][0], acc[mi][1], acc[mi][2], acc[mi][3]);
    }
}

// Same GEMM but A is bf16 in [t][j][b] layout: A[m][k] = embt[(m&127)*8192 + k*16 + (m>>7)]
// M fixed 2048 (grid.y=128).
__global__ __launch_bounds__(256) void k_gemm_tl(
    const unsigned short* __restrict__ embt, const float* __restrict__ Wt,
    const float* __restrict__ bias, float* __restrict__ out,
    int K, int N)
{
    int z = blockIdx.z;
    const float* Wtz = Wt + (size_t)z * K * N;
    float* outz = out + (size_t)z * 2048 * N;
    const float* biasz = bias + (size_t)z * N;

    __shared__ float As[16 * 512];
    int tid = threadIdx.x;
    int mq = tid >> 6;
    int nq = tid & 63;
    int n0 = blockIdx.x * 256 + nq * 4;
    int mbase = blockIdx.y * 16;
    int bb = mbase >> 7;        // batch (same for all 16 rows)
    int tt0 = mbase & 127;      // t of row 0

    for (int r = 0; r < 16; ++r) {
        const unsigned short* Ar = embt + (size_t)(tt0 + r) * 8192 + bb;
        for (int c = tid; c < K; c += 256) As[r * K + c] = bf2f(Ar[c * 16]);
    }
    __syncthreads();

    float4 bv = *(const float4*)(biasz + n0);
    float acc[4][4];
#pragma unroll
    for (int mi = 0; mi < 4; mi++) { acc[mi][0] = bv.x; acc[mi][1] = bv.y; acc[mi][2] = bv.z; acc[mi][3] = bv.w; }

    const float* asr = As + (mq * 4) * K;
    for (int k = 0; k < K; ++k) {
        float4 w = *(const float4*)(Wtz + (size_t)k * N + n0);
        float x0 = asr[k];
        float x1 = asr[K + k];
        float x2 = asr[2 * K + k];
        float x3 = asr[3 * K + k];
        acc[0][0] += x0 * w.x; acc[0][1] += x0 * w.y; acc[0][2] += x0 * w.z; acc[0][3] += x0 * w.w;
        acc[1][0] += x1 * w.x; acc[1][1] += x1 * w.y; acc[1][2] += x1 * w.z; acc[1][3] += x1 * w.w;
        acc[2][0] += x2 * w.x; acc[2][1] += x2 * w.y; acc[2][2] += x2 * w.z; acc[2][3] += x2 * w.w;
        acc[3][0] += x3 * w.x; acc[3][1] += x3 * w.y; acc[3][2] += x3 * w.z; acc[3][3] += x3 * w.w;
    }
#pragma unroll
    for (int mi = 0; mi < 4; mi++) {
        size_t m = (size_t)mbase + mq * 4 + mi;
        *(float4*)(outz + m * N + n0) = make_float4(acc[mi][0], acc[mi][1], acc[mi][2], acc[mi][3]);
    }
}

// ---------------- MFMA LSTM recurrence: one block per direction (R2-exact + coalesced emb store) ----
#define GATE(A, C, H) { \
    float gi = A[0], gf = A[1], gg = A[2], go = A[3]; \
    float si = __builtin_amdgcn_rcpf(1.f + __expf(-gi)); \
    float sf = __builtin_amdgcn_rcpf(1.f + __expf(-gf)); \
    float so = __builtin_amdgcn_rcpf(1.f + __expf(-go)); \
    float eg = __expf(2.f * gg); \
    float tg = 1.f - 2.f * __builtin_amdgcn_rcpf(eg + 1.f); \
    C = sf * C + si * tg; \
    float ec = __expf(2.f * C); \
    float tc = 1.f - 2.f * __builtin_amdgcn_rcpf(ec + 1.f); \
    H = so * tc; }

__global__ __launch_bounds__(1024) void k_lstm_mfma(
    const float* __restrict__ xgf,            // [2][128][16][4][64][4]
    const unsigned short* __restrict__ Wfrag, // [2][16][8][4][64][8] bf16
    unsigned short* __restrict__ embt)        // [128][512][16] bf16 ([t][j][b]); dir d writes j in d*256..
{
    const int d = blockIdx.x;
    const int tid = threadIdx.x;
    const int w = tid >> 6;
    const int l = tid & 63;
    const int b = l & 15;
    const int jh = l >> 4;

    __shared__ unsigned short Wlds[8 * 16 * 64 * 8];  // 128 KiB: slots (ks2*4+t)
    __shared__ unsigned short hB[32 * 16 * 8];        // 8 KiB: [kblk][b][e]

    // register-resident weights ks=0..5
    const unsigned short* wgp = Wfrag + ((size_t)(d * 16 + w)) * (8 * 4 * 64 * 8);
    bf16x8 Wr[6][4];
#pragma unroll
    for (int ks = 0; ks < 6; ++ks)
#pragma unroll
        for (int t4 = 0; t4 < 4; ++t4)
            Wr[ks][t4] = *(const bf16x8*)(wgp + ((ks * 4 + t4) * 64 + l) * 8);
    // LDS-resident weights ks=6,7
#pragma unroll
    for (int ks2 = 0; ks2 < 2; ++ks2)
#pragma unroll
        for (int t4 = 0; t4 < 4; ++t4) {
            bf16x8 v = *(const bf16x8*)(wgp + (((6 + ks2) * 4 + t4) * 64 + l) * 8);
            *(bf16x8*)(&Wlds[(ks2 * 4 + t4) * 8192 + w * 512 + l * 8]) = v;
        }
    // zero h state
    *(uint2*)(&hB[tid * 4]) = make_uint2(0u, 0u);

    const int sgn = d ? -1 : 1;
    int t = d ? 127 : 0;
    const f32x4* xb = (const f32x4*)(xgf) + (size_t)d * 524288;
    const int xo = w * 256 + l;

    f32x4 a0 = xb[t * 4096 + xo];
    f32x4 a1 = xb[t * 4096 + xo + 64];
    f32x4 a2 = xb[t * 4096 + xo + 128];
    f32x4 a3 = xb[t * 4096 + xo + 192];

    float c0 = 0.f, c1 = 0.f, c2 = 0.f, c3 = 0.f;
    const int hoff = jh * 128 + b * 8;     // + ks*512
    const int wloff = w * 512 + l * 8;     // + slot*8192
    const int hwoff = w * 256 + b * 8 + jh;
    // coalesced emb store base: lane-varying part is exactly +l (128 B contiguous per wave store)
    unsigned short* embp = embt + (size_t)d * 4096 + (size_t)w * 256 + l;
    __syncthreads();

    for (int s = 0; s < 128; ++s) {
#pragma unroll
        for (int ks = 0; ks < 6; ++ks) {
            bf16x8 hf = *(const bf16x8*)(&hB[ks * 512 + hoff]);
            a0 = __builtin_amdgcn_mfma_f32_16x16x32_bf16(Wr[ks][0], hf, a0, 0, 0, 0);
            a1 = __builtin_amdgcn_mfma_f32_16x16x32_bf16(Wr[ks][1], hf, a1, 0, 0, 0);
            a2 = __builtin_amdgcn_mfma_f32_16x16x32_bf16(Wr[ks][2], hf, a2, 0, 0, 0);
            a3 = __builtin_amdgcn_mfma_f32_16x16x32_bf16(Wr[ks][3], hf, a3, 0, 0, 0);
        }
        {
            bf16x8 hf = *(const bf16x8*)(&hB[6 * 512 + hoff]);
            bf16x8 w0 = *(const bf16x8*)(&Wlds[0 * 8192 + wloff]);
            bf16x8 w1 = *(const bf16x8*)(&Wlds[1 * 8192 + wloff]);
            bf16x8 w2 = *(const bf16x8*)(&Wlds[2 * 8192 + wloff]);
            bf16x8 w3 = *(const bf16x8*)(&Wlds[3 * 8192 + wloff]);
            a0 = __builtin_amdgcn_mfma_f32_16x16x32_bf16(w0, hf, a0, 0, 0, 0);
            a1 = __builtin_amdgcn_mfma_f32_16x16x32_bf16(w1, hf, a1, 0, 0, 0);
            a2 = __builtin_amdgcn_mfma_f32_16x16x32_bf16(w2, hf, a2, 0, 0, 0);
            a3 = __builtin_amdgcn_mfma_f32_16x16x32_bf16(w3, hf, a3, 0, 0, 0);
        }
        {
            bf16x8 hf = *(const bf16x8*)(&hB[7 * 512 + hoff]);
            bf16x8 w0 = *(const bf16x8*)(&Wlds[4 * 8192 + wloff]);
            bf16x8 w1 = *(const bf16x8*)(&Wlds[5 * 8192 + wloff]);
            bf16x8 w2 = *(const bf16x8*)(&Wlds[6 * 8192 + wloff]);
            bf16x8 w3 = *(const bf16x8*)(&Wlds[7 * 8192 + wloff]);
            a0 = __builtin_amdgcn_mfma_f32_16x16x32_bf16(w0, hf, a0, 0, 0, 0);
            a1 = __builtin_amdgcn_mfma_f32_16x16x32_bf16(w1, hf, a1, 0, 0, 0);
            a2 = __builtin_amdgcn_mfma_f32_16x16x32_bf16(w2, hf, a2, 0, 0, 0);
            a3 = __builtin_amdgcn_mfma_f32_16x16x32_bf16(w3, hf, a3, 0, 0, 0);
        }
        // gate nonlinearity (acc includes xg + biases via C-init)
        float h0, h1, h2, h3;
        GATE(a0, c0, h0);
        GATE(a1, c1, h1);
        GATE(a2, c2, h2);
        GATE(a3, c3, h3);
        unsigned short u0 = f2bf(h0), u1 = f2bf(h1), u2 = f2bf(h2), u3 = f2bf(h3);
        // emb global write: [t][j][b] layout -> 4 fully-coalesced 128B wave stores
        {
            unsigned short* ep = embp + (size_t)t * 8192;
            ep[0]   = u0;   // t4=0
            ep[64]  = u1;   // t4=1
            ep[128] = u2;   // t4=2
            ep[192] = u3;   // t4=3
        }
        // prefetch next step's xg into acc (drained by the barrier)
        int tn = (s == 127) ? t : (t + sgn);
        a0 = xb[tn * 4096 + xo];
        a1 = xb[tn * 4096 + xo + 64];
        a2 = xb[tn * 4096 + xo + 128];
        a3 = xb[tn * 4096 + xo + 192];
        __syncthreads();   // all reads of h_{s-1} complete
        hB[hwoff] = u0;
        hB[hwoff + 4] = u1;
        hB[hwoff + 128] = u2;
        hB[hwoff + 132] = u3;
        __syncthreads();   // h_s visible
        t = tn;
    }
}

// ---------------- fused pairwise scorer ----------------
__global__ __launch_bounds__(256) void k_scorer(
    const float* __restrict__ HaHb, const float* __restrict__ W2,
    const float* __restrict__ b2, const float* __restrict__ W3,
    const float* __restrict__ b3v, float* __restrict__ score)
{
    int jt = blockIdx.x;
    int i  = blockIdx.y;
    int b  = blockIdx.z;
    int tid = threadIdx.x;

    __shared__ __align__(16) float ha[256];
    __shared__ __align__(16) float h1[32 * 260];
    __shared__ __align__(16) float w2s[128 * 36];

    ha[tid] = HaHb[(size_t)(b * 128 + i) * 512 + tid];
    __syncthreads();

    {
        int j = tid >> 3;
        int q = tid & 7;
        const float* hbrow = HaHb + (size_t)(b * 128 + jt * 32 + j) * 512 + 256;
        float* h1r = h1 + j * 260;
#pragma unroll
        for (int cc = 0; cc < 32; ++cc) {
            int c = q + cc * 8;
            float v = ha[c] + hbrow[c];
            h1r[c] = v > 0.f ? v : 0.f;
        }
    }

    float acc[4][4] = {};
    int jq = tid >> 5;
    int rq = tid & 31;

    for (int ch = 0; ch < 8; ++ch) {
        int cb = ch * 32;
        __syncthreads();
        for (int idx = tid; idx < 128 * 32; idx += 256) {
            int r = idx >> 5, cc = idx & 31;
            w2s[r * 36 + cc] = W2[(size_t)r * 256 + cb + cc];
        }
        __syncthreads();
#pragma unroll
        for (int cc = 0; cc < 32; cc += 4) {
            float4 hv[4], wv[4];
#pragma unroll
            for (int jj = 0; jj < 4; ++jj)
                hv[jj] = *(const float4*)(h1 + (jq + jj * 8) * 260 + cb + cc);
#pragma unroll
            for (int rr = 0; rr < 4; ++rr)
                wv[rr] = *(const float4*)(w2s + (rq + rr * 32) * 36 + cc);
#pragma unroll
            for (int jj = 0; jj < 4; ++jj)
#pragma unroll
                for (int rr = 0; rr < 4; ++rr)
                    acc[jj][rr] += hv[jj].x * wv[rr].x + hv[jj].y * wv[rr].y +
                                   hv[jj].z * wv[rr].z + hv[jj].w * wv[rr].w;
        }
    }

    float part0 = 0.f, part1 = 0.f, part2 = 0.f, part3 = 0.f;
#pragma unroll
    for (int rr = 0; rr < 4; ++rr) {
        int r = rq + rr * 32;
        float bb = b2[r], ww = W3[r];
        float t0 = acc[0][rr] + bb; if (t0 > 0.f) part0 += t0 * ww;
        float t1 = acc[1][rr] + bb; if (t1 > 0.f) part1 += t1 * ww;
        float t2 = acc[2][rr] + bb; if (t2 > 0.f) part2 += t2 * ww;
        float t3 = acc[3][rr] + bb; if (t3 > 0.f) part3 += t3 * ww;
    }
#pragma unroll
    for (int off = 16; off >= 1; off >>= 1) {
        part0 += __shfl_xor(part0, off, 32);
        part1 += __shfl_xor(part1, off, 32);
        part2 += __shfl_xor(part2, off, 32);
        part3 += __shfl_xor(part3, off, 32);
    }
    if (rq == 0) {
        float bb3 = b3v[0];
        float p[4] = {part0, part1, part2, part3};
#pragma unroll
        for (int jj = 0; jj < 4; ++jj) {
            int jg = jt * 32 + jq + jj * 8;
            float sc = p[jj] + bb3;
            sc = sc > 0.f ? sc : 0.f;
            if (jg == i || jg == 0) sc = 0.f;
            score[(size_t)(b * 128 + i) * 128 + jg] = sc;
        }
    }
}

// ---------------- loss ----------------
__global__ __launch_bounds__(128) void k_loss1(
    const float* __restrict__ score, const int* __restrict__ tree, float* __restrict__ res)
{
    int k = blockIdx.x;
    int b = blockIdx.y;
    int head = tree[((size_t)b * 128 + k + 1) * 2 + 0];
    int dep  = tree[((size_t)b * 128 + k + 1) * 2 + 1];
    int i = threadIdx.x;
    float s = score[((size_t)b * 128 + i) * 128 + dep];
    float v = (i == dep) ? 0.f : __expf(s);
    __shared__ float redu[2];
#pragma unroll
    for (int off = 32; off >= 1; off >>= 1) v += __shfl_down(v, off, 64);
    if ((i & 63) == 0) redu[i >> 6] = v;
    __syncthreads();
    if (i == 0) {
        float norm = redu[0] + redu[1];
        float num = score[((size_t)b * 128 + head) * 128 + dep];
        res[b * 127 + k] = __logf(norm) - num;
    }
}

__global__ __launch_bounds__(256) void k_loss2(const float* __restrict__ res, float* __restrict__ out) {
    int tid = threadIdx.x;
    float a = 0.f;
    for (int idx = tid; idx < 16 * 127; idx += 256) a += res[idx];
    __shared__ float sm[256];
    sm[tid] = a;
    __syncthreads();
    for (int off = 128; off >= 1; off >>= 1) {
        if (tid < off) sm[tid] += sm[tid + off];
        __syncthreads();
    }
    if (tid == 0) out[0] = sm[0] / 127.f;
}

// ---------------- host launcher ----------------
extern "C" void kernel_launch(void* const* d_in, const int* in_sizes, int n_in,
                              void* d_out, int out_size, void* d_ws, size_t ws_size,
                              hipStream_t stream) {
    (void)in_sizes; (void)n_in; (void)out_size; (void)ws_size;
    const float* X    = (const float*)d_in[0];
    const float* Wih0 = (const float*)d_in[1];
    const float* Whh0 = (const float*)d_in[2];
    const float* bih0 = (const float*)d_in[3];
    const float* bhh0 = (const float*)d_in[4];
    const float* Wih1 = (const float*)d_in[5];
    const float* Whh1 = (const float*)d_in[6];
    const float* bih1 = (const float*)d_in[7];
    const float* bhh1 = (const float*)d_in[8];
    const float* W1   = (const float*)d_in[9];
    const float* b1   = (const float*)d_in[10];
    const float* W2   = (const float*)d_in[11];
    const float* b2   = (const float*)d_in[12];
    const float* W3   = (const float*)d_in[13];
    const float* b3   = (const float*)d_in[14];
    const int*   tree = (const int*)d_in[15];
    float* out = (float*)d_out;   // [0]=loss, [1..]=score

    float* ws = (float*)d_ws;
    size_t o = 0;
    float* WihT0 = ws + o; o += (size_t)2 * 200 * 1024;
    float* WihT1 = ws + o; o += (size_t)2 * 512 * 1024;
    float* W1T   = ws + o; o += (size_t)512 * 512;
    float* bsum0 = ws + o; o += 2048;
    float* bsum1 = ws + o; o += 2048;
    float* bhab  = ws + o; o += 512;
    unsigned short* Wf0 = (unsigned short*)(ws + o); o += (size_t)2 * 16 * 8 * 4 * 64 * 8 / 2;
    unsigned short* Wf1 = (unsigned short*)(ws + o); o += (size_t)2 * 16 * 8 * 4 * 64 * 8 / 2;
    float* xg   = ws + o; o += (size_t)2 * 2048 * 1024;   // shared between layers
    float* xgf  = ws + o; o += (size_t)2 * 2048 * 1024;   // shared between layers
    unsigned short* embt0 = (unsigned short*)(ws + o); o += (size_t)128 * 512 * 16 / 2;
    unsigned short* embt1 = (unsigned short*)(ws + o); o += (size_t)128 * 512 * 16 / 2;
    float* HaHb = ws + o; o += (size_t)2048 * 512;
    float* res  = ws + o; o += 2048;

    // prep
    k_transpose_N1024<<<dim3(800, 1, 2), 256, 0, stream>>>(Wih0, WihT0, 200);
    k_transpose_N1024<<<dim3(2048, 1, 2), 256, 0, stream>>>(Wih1, WihT1, 512);
    k_wfrag<<<256, 256, 0, stream>>>(Whh0, Wf0);
    k_wfrag<<<256, 256, 0, stream>>>(Whh1, Wf1);
    k_w1t<<<1024, 256, 0, stream>>>(W1, W1T);
    k_bias<<<18, 256, 0, stream>>>(bih0, bhh0, bih1, bhh1, b1, bsum0, bsum1, bhab);

    // layer 0
    k_gemm<<<dim3(4, 128, 2), 256, 0, stream>>>(X, WihT0, bsum0, xg, 2048, 200, 1024);
    k_reorder<<<4096, 256, 0, stream>>>(xg, xgf);
    k_lstm_mfma<<<2, 1024, 0, stream>>>(xgf, Wf0, embt0);
    // layer 1 (A from [t][j][b] bf16 layout)
    k_gemm_tl<<<dim3(4, 128, 2), 256, 0, stream>>>(embt0, WihT1, bsum1, xg, 512, 1024);
    k_reorder<<<4096, 256, 0, stream>>>(xg, xgf);
    k_lstm_mfma<<<2, 1024, 0, stream>>>(xgf, Wf1, embt1);
    // Ha|Hb (A from [t][j][b] bf16 layout)
    k_gemm_tl<<<dim3(2, 128, 1), 256, 0, stream>>>(embt1, W1T, bhab, HaHb, 512, 512);
    // scorer -> out+1
    k_scorer<<<dim3(4, 128, 16), 256, 0, stream>>>(HaHb, W2, b2, W3, b3, out + 1);
    // loss
    k_loss1<<<dim3(127, 16), 128, 0, stream>>>(out + 1, tree, res);
    k_loss2<<<1, 256, 0, stream>>>(res, out);
}

// Round 7
// 979.965 us; speedup vs baseline: 3.0579x; 1.3361x over previous
//
#include <hip/hip_runtime.h>
#include <hip/hip_bf16.h>
#include <cstdint>
#include <cstddef>

// B=16, S=128, IN=200, H=256, 4H=1024, 2H=512

typedef __attribute__((ext_vector_type(8))) short bf16x8;
typedef __attribute__((ext_vector_type(4))) float f32x4;
typedef __attribute__((ext_vector_type(4))) unsigned short u16x4;

__device__ __forceinline__ float bf2f(unsigned short u) {
    return __uint_as_float(((unsigned)u) << 16);
}
__device__ __forceinline__ unsigned short f2bf(float f) {
    unsigned u = __float_as_uint(f);
    u = (u + 0x7FFFu + ((u >> 16) & 1u)) >> 16;
    return (unsigned short)u;
}

// ---------------- prep kernels ----------------

// dst[z][k][n] = src[z][n][k], n<1024, k<K
__global__ void k_transpose_N1024(const float* __restrict__ src, float* __restrict__ dst, int K) {
    int z = blockIdx.z;
    int idx = blockIdx.x * 256 + threadIdx.x;
    if (idx >= K * 1024) return;
    int k = idx >> 10, n = idx & 1023;
    dst[(size_t)z * K * 1024 + idx] = src[(size_t)z * 1024 * K + (size_t)n * K + k];
}

// Whh (2,1024,256) fp32 -> A-fragment layout bf16
__global__ void k_wfrag(const float* __restrict__ Whh, unsigned short* __restrict__ Wfrag) {
    int idx = blockIdx.x * 256 + threadIdx.x;   // 65536 total
    int l = idx & 63;
    int t = (idx >> 6) & 3;
    int ks = (idx >> 8) & 7;
    int w = (idx >> 11) & 15;
    int d = idx >> 15;
    int r = l & 15;
    int kbase = ks * 32 + (l >> 4) * 8;
    int row = (r & 3) * 256 + w * 16 + t * 4 + (r >> 2);
    const float* src = Whh + (size_t)d * (1024 * 256) + (size_t)row * 256 + kbase;
    unsigned short* dst = Wfrag + (size_t)idx * 8;
#pragma unroll
    for (int e = 0; e < 8; ++e) dst[e] = f2bf(src[e]);
}

// W2 (128,256) fp32 -> B-fragment layout bf16: w2f[((nt*8+ks)*64+l)*8+e] =
//   bf16(W2[nt*16+(l&15)][ks*32+(l>>4)*8+e])
__global__ void k_w2frag(const float* __restrict__ W2, unsigned short* __restrict__ w2f) {
    int idx = blockIdx.x * 256 + threadIdx.x;   // 4096 total
    if (idx >= 4096) return;
    int l = idx & 63;
    int ks = (idx >> 6) & 7;
    int nt = idx >> 9;
    const float* src = W2 + (size_t)(nt * 16 + (l & 15)) * 256 + ks * 32 + (l >> 4) * 8;
    unsigned short* dst = w2f + (size_t)idx * 8;
#pragma unroll
    for (int e = 0; e < 8; ++e) dst[e] = f2bf(src[e]);
}

// W1 (256,1024) -> dst[k][o], k<512, o<512
__global__ void k_w1t(const float* __restrict__ W1, float* __restrict__ dst) {
    int idx = blockIdx.x * 256 + threadIdx.x;
    if (idx >= 512 * 512) return;
    int k = idx >> 9, o = idx & 511;
    dst[idx] = (o < 256) ? W1[(size_t)o * 1024 + k] : W1[(size_t)(o - 256) * 1024 + 512 + k];
}

__global__ void k_bias(const float* __restrict__ bih0, const float* __restrict__ bhh0,
                       const float* __restrict__ bih1, const float* __restrict__ bhh1,
                       const float* __restrict__ b1,
                       float* __restrict__ bsum0, float* __restrict__ bsum1, float* __restrict__ bhab) {
    int idx = blockIdx.x * 256 + threadIdx.x;
    if (idx < 2048) bsum0[idx] = bih0[idx] + bhh0[idx];
    else if (idx < 4096) { int i = idx - 2048; bsum1[i] = bih1[i] + bhh1[i]; }
    else if (idx < 4608) { int i = idx - 4096; bhab[i] = (i < 256) ? b1[i] : 0.f; }
}

// xg[d][b*128+t][n] -> xgfrag
__global__ __launch_bounds__(256) void k_reorder(const float* __restrict__ xg, float* __restrict__ xgf) {
    int idx = blockIdx.x * 256 + threadIdx.x;   // 1048576 total
    int n4 = idx & 255;
    int m = (idx >> 8) & 2047;
    int d = idx >> 19;
    int n0 = n4 * 4;
    int q = n0 >> 8;
    int jbase = n0 & 255;
    int b = m >> 7, t = m & 127;
    float4 v = *(const float4*)(xg + ((size_t)(d * 2048 + m)) * 1024 + n0);
    float* base = xgf + (size_t)d * 2097152;
    float vv[4] = {v.x, v.y, v.z, v.w};
#pragma unroll
    for (int dj = 0; dj < 4; ++dj) {
        int j = jbase + dj;
        int fi = (t * 4096 + (j >> 4) * 256 + ((j >> 2) & 3) * 64 + dj * 16 + b) * 4 + q;
        base[fi] = vv[dj];
    }
}

// ---------------- generic GEMM ----------------
__global__ __launch_bounds__(256) void k_gemm(
    const float* __restrict__ A, const float* __restrict__ Wt,
    const float* __restrict__ bias, float* __restrict__ out,
    int M, int K, int N)
{
    int z = blockIdx.z;
    const float* Wtz = Wt + (size_t)z * K * N;
    float* outz = out + (size_t)z * M * N;
    const float* biasz = bias + (size_t)z * N;

    __shared__ float As[16 * 512];
    int tid = threadIdx.x;
    int mq = tid >> 6;
    int nq = tid & 63;
    int n0 = blockIdx.x * 256 + nq * 4;
    int mbase = blockIdx.y * 16;

    for (int r = 0; r < 16; ++r) {
        const float* Ar = A + (size_t)(mbase + r) * K;
        for (int c = tid; c < K; c += 256) As[r * K + c] = Ar[c];
    }
    __syncthreads();

    float4 bv = *(const float4*)(biasz + n0);
    float acc[4][4];
#pragma unroll
    for (int mi = 0; mi < 4; mi++) { acc[mi][0] = bv.x; acc[mi][1] = bv.y; acc[mi][2] = bv.z; acc[mi][3] = bv.w; }

    const float* asr = As + (mq * 4) * K;
    for (int k = 0; k < K; ++k) {
        float4 w = *(const float4*)(Wtz + (size_t)k * N + n0);
        float x0 = asr[k];
        float x1 = asr[K + k];
        float x2 = asr[2 * K + k];
        float x3 = asr[3 * K + k];
        acc[0][0] += x0 * w.x; acc[0][1] += x0 * w.y; acc[0][2] += x0 * w.z; acc[0][3] += x0 * w.w;
        acc[1][0] += x1 * w.x; acc[1][1] += x1 * w.y; acc[1][2] += x1 * w.z; acc[1][3] += x1 * w.w;
        acc[2][0] += x2 * w.x; acc[2][1] += x2 * w.y; acc[2][2] += x2 * w.z; acc[2][3] += x2 * w.w;
        acc[3][0] += x3 * w.x; acc[3][1] += x3 * w.y; acc[3][2] += x3 * w.z; acc[3][3] += x3 * w.w;
    }
#pragma unroll
    for (int mi = 0; mi < 4; mi++) {
        size_t m = (size_t)mbase + mq * 4 + mi;
        *(float4*)(outz + m * N + n0) = make_float4(acc[mi][0], acc[mi][1], acc[mi][2], acc[mi][3]);
    }
}

// Same GEMM but A is bf16 in [t][j][b] layout
__global__ __launch_bounds__(256) void k_gemm_tl(
    const unsigned short* __restrict__ embt, const float* __restrict__ Wt,
    const float* __restrict__ bias, float* __restrict__ out,
    int K, int N)
{
    int z = blockIdx.z;
    const float* Wtz = Wt + (size_t)z * K * N;
    float* outz = out + (size_t)z * 2048 * N;
    const float* biasz = bias + (size_t)z * N;

    __shared__ float As[16 * 512];
    int tid = threadIdx.x;
    int mq = tid >> 6;
    int nq = tid & 63;
    int n0 = blockIdx.x * 256 + nq * 4;
    int mbase = blockIdx.y * 16;
    int bb = mbase >> 7;
    int tt0 = mbase & 127;

    for (int r = 0; r < 16; ++r) {
        const unsigned short* Ar = embt + (size_t)(tt0 + r) * 8192 + bb;
        for (int c = tid; c < K; c += 256) As[r * K + c] = bf2f(Ar[c * 16]);
    }
    __syncthreads();

    float4 bv = *(const float4*)(biasz + n0);
    float acc[4][4];
#pragma unroll
    for (int mi = 0; mi < 4; mi++) { acc[mi][0] = bv.x; acc[mi][1] = bv.y; acc[mi][2] = bv.z; acc[mi][3] = bv.w; }

    const float* asr = As + (mq * 4) * K;
    for (int k = 0; k < K; ++k) {
        float4 w = *(const float4*)(Wtz + (size_t)k * N + n0);
        float x0 = asr[k];
        float x1 = asr[K + k];
        float x2 = asr[2 * K + k];
        float x3 = asr[3 * K + k];
        acc[0][0] += x0 * w.x; acc[0][1] += x0 * w.y; acc[0][2] += x0 * w.z; acc[0][3] += x0 * w.w;
        acc[1][0] += x1 * w.x; acc[1][1] += x1 * w.y; acc[1][2] += x1 * w.z; acc[1][3] += x1 * w.w;
        acc[2][0] += x2 * w.x; acc[2][1] += x2 * w.y; acc[2][2] += x2 * w.z; acc[2][3] += x2 * w.w;
        acc[3][0] += x3 * w.x; acc[3][1] += x3 * w.y; acc[3][2] += x3 * w.z; acc[3][3] += x3 * w.w;
    }
#pragma unroll
    for (int mi = 0; mi < 4; mi++) {
        size_t m = (size_t)mbase + mq * 4 + mi;
        *(float4*)(outz + m * N + n0) = make_float4(acc[mi][0], acc[mi][1], acc[mi][2], acc[mi][3]);
    }
}

// ---------------- MFMA LSTM recurrence (R6 winner, unchanged) ----------------
#define GATE(A, C, H) { \
    float gi = A[0], gf = A[1], gg = A[2], go = A[3]; \
    float si = __builtin_amdgcn_rcpf(1.f + __expf(-gi)); \
    float sf = __builtin_amdgcn_rcpf(1.f + __expf(-gf)); \
    float so = __builtin_amdgcn_rcpf(1.f + __expf(-go)); \
    float eg = __expf(2.f * gg); \
    float tg = 1.f - 2.f * __builtin_amdgcn_rcpf(eg + 1.f); \
    C = sf * C + si * tg; \
    float ec = __expf(2.f * C); \
    float tc = 1.f - 2.f * __builtin_amdgcn_rcpf(ec + 1.f); \
    H = so * tc; }

__global__ __launch_bounds__(1024) void k_lstm_mfma(
    const float* __restrict__ xgf,            // [2][128][16][4][64][4]
    const unsigned short* __restrict__ Wfrag, // [2][16][8][4][64][8] bf16
    unsigned short* __restrict__ embt)        // [128][512][16] bf16 ([t][j][b])
{
    const int d = blockIdx.x;
    const int tid = threadIdx.x;
    const int w = tid >> 6;
    const int l = tid & 63;
    const int b = l & 15;
    const int jh = l >> 4;

    __shared__ unsigned short Wlds[8 * 16 * 64 * 8];
    __shared__ unsigned short hB[32 * 16 * 8];

    const unsigned short* wgp = Wfrag + ((size_t)(d * 16 + w)) * (8 * 4 * 64 * 8);
    bf16x8 Wr[6][4];
#pragma unroll
    for (int ks = 0; ks < 6; ++ks)
#pragma unroll
        for (int t4 = 0; t4 < 4; ++t4)
            Wr[ks][t4] = *(const bf16x8*)(wgp + ((ks * 4 + t4) * 64 + l) * 8);
#pragma unroll
    for (int ks2 = 0; ks2 < 2; ++ks2)
#pragma unroll
        for (int t4 = 0; t4 < 4; ++t4) {
            bf16x8 v = *(const bf16x8*)(wgp + (((6 + ks2) * 4 + t4) * 64 + l) * 8);
            *(bf16x8*)(&Wlds[(ks2 * 4 + t4) * 8192 + w * 512 + l * 8]) = v;
        }
    *(uint2*)(&hB[tid * 4]) = make_uint2(0u, 0u);

    const int sgn = d ? -1 : 1;
    int t = d ? 127 : 0;
    const f32x4* xb = (const f32x4*)(xgf) + (size_t)d * 524288;
    const int xo = w * 256 + l;

    f32x4 a0 = xb[t * 4096 + xo];
    f32x4 a1 = xb[t * 4096 + xo + 64];
    f32x4 a2 = xb[t * 4096 + xo + 128];
    f32x4 a3 = xb[t * 4096 + xo + 192];

    float c0 = 0.f, c1 = 0.f, c2 = 0.f, c3 = 0.f;
    const int hoff = jh * 128 + b * 8;
    const int wloff = w * 512 + l * 8;
    const int hwoff = w * 256 + b * 8 + jh;
    unsigned short* embp = embt + (size_t)d * 4096 + (size_t)w * 256 + l;
    __syncthreads();

    for (int s = 0; s < 128; ++s) {
#pragma unroll
        for (int ks = 0; ks < 6; ++ks) {
            bf16x8 hf = *(const bf16x8*)(&hB[ks * 512 + hoff]);
            a0 = __builtin_amdgcn_mfma_f32_16x16x32_bf16(Wr[ks][0], hf, a0, 0, 0, 0);
            a1 = __builtin_amdgcn_mfma_f32_16x16x32_bf16(Wr[ks][1], hf, a1, 0, 0, 0);
            a2 = __builtin_amdgcn_mfma_f32_16x16x32_bf16(Wr[ks][2], hf, a2, 0, 0, 0);
            a3 = __builtin_amdgcn_mfma_f32_16x16x32_bf16(Wr[ks][3], hf, a3, 0, 0, 0);
        }
        {
            bf16x8 hf = *(const bf16x8*)(&hB[6 * 512 + hoff]);
            bf16x8 w0 = *(const bf16x8*)(&Wlds[0 * 8192 + wloff]);
            bf16x8 w1 = *(const bf16x8*)(&Wlds[1 * 8192 + wloff]);
            bf16x8 w2 = *(const bf16x8*)(&Wlds[2 * 8192 + wloff]);
            bf16x8 w3 = *(const bf16x8*)(&Wlds[3 * 8192 + wloff]);
            a0 = __builtin_amdgcn_mfma_f32_16x16x32_bf16(w0, hf, a0, 0, 0, 0);
            a1 = __builtin_amdgcn_mfma_f32_16x16x32_bf16(w1, hf, a1, 0, 0, 0);
            a2 = __builtin_amdgcn_mfma_f32_16x16x32_bf16(w2, hf, a2, 0, 0, 0);
            a3 = __builtin_amdgcn_mfma_f32_16x16x32_bf16(w3, hf, a3, 0, 0, 0);
        }
        {
            bf16x8 hf = *(const bf16x8*)(&hB[7 * 512 + hoff]);
            bf16x8 w0 = *(const bf16x8*)(&Wlds[4 * 8192 + wloff]);
            bf16x8 w1 = *(const bf16x8*)(&Wlds[5 * 8192 + wloff]);
            bf16x8 w2 = *(const bf16x8*)(&Wlds[6 * 8192 + wloff]);
            bf16x8 w3 = *(const bf16x8*)(&Wlds[7 * 8192 + wloff]);
            a0 = __builtin_amdgcn_mfma_f32_16x16x32_bf16(w0, hf, a0, 0, 0, 0);
            a1 = __builtin_amdgcn_mfma_f32_16x16x32_bf16(w1, hf, a1, 0, 0, 0);
            a2 = __builtin_amdgcn_mfma_f32_16x16x32_bf16(w2, hf, a2, 0, 0, 0);
            a3 = __builtin_amdgcn_mfma_f32_16x16x32_bf16(w3, hf, a3, 0, 0, 0);
        }
        float h0, h1, h2, h3;
        GATE(a0, c0, h0);
        GATE(a1, c1, h1);
        GATE(a2, c2, h2);
        GATE(a3, c3, h3);
        unsigned short u0 = f2bf(h0), u1 = f2bf(h1), u2 = f2bf(h2), u3 = f2bf(h3);
        {
            unsigned short* ep = embp + (size_t)t * 8192;
            ep[0]   = u0;
            ep[64]  = u1;
            ep[128] = u2;
            ep[192] = u3;
        }
        int tn = (s == 127) ? t : (t + sgn);
        a0 = xb[tn * 4096 + xo];
        a1 = xb[tn * 4096 + xo + 64];
        a2 = xb[tn * 4096 + xo + 128];
        a3 = xb[tn * 4096 + xo + 192];
        __syncthreads();
        hB[hwoff] = u0;
        hB[hwoff + 4] = u1;
        hB[hwoff + 128] = u2;
        hB[hwoff + 132] = u3;
        __syncthreads();
        t = tn;
    }
}

// ---------------- MFMA pairwise scorer ----------------
// grid (jt=8, it=8, b=16), block 256 (4 waves). Wave w owns i rows i0+4w..i0+4w+3.
// h2 = relu(h1 @ W2^T + b2), score = relu(h2 @ W3 + b3) with mask.
__global__ __launch_bounds__(256, 2) void k_scorer_mfma(
    const float* __restrict__ HaHb, const unsigned short* __restrict__ w2f,
    const float* __restrict__ b2, const float* __restrict__ W3,
    const float* __restrict__ b3v, float* __restrict__ score)
{
    const int jt = blockIdx.x, it = blockIdx.y, b = blockIdx.z;
    const int j0 = jt * 16, i0 = it * 16;
    const int tid = threadIdx.x;
    const int w = tid >> 6;
    const int l = tid & 63;
    const int n_l = l & 15;
    const int kq = l >> 4;

    __shared__ __align__(16) unsigned short HaS[16 * 264];
    __shared__ __align__(16) unsigned short HbS[16 * 264];

    // stage Ha (cols 0..255 of rows i0..) and Hb (cols 256.. of rows j0..) as bf16
    {
        const float* base = HaHb + ((size_t)(b * 128)) * 512;
        int rr = tid >> 4;
        int q = tid & 15;
#pragma unroll
        for (int rep = 0; rep < 4; ++rep) {
            int k0 = q * 4 + rep * 64;
            float4 va = *(const float4*)(base + (size_t)(i0 + rr) * 512 + k0);
            float4 vb = *(const float4*)(base + (size_t)(j0 + rr) * 512 + 256 + k0);
            u16x4 ua = { f2bf(va.x), f2bf(va.y), f2bf(va.z), f2bf(va.w) };
            u16x4 ub = { f2bf(vb.x), f2bf(vb.y), f2bf(vb.z), f2bf(vb.w) };
            *(u16x4*)(&HaS[rr * 264 + k0]) = ua;
            *(u16x4*)(&HbS[rr * 264 + k0]) = ub;
        }
    }

    // per-lane epilogue constants
    float b2v[8], w3v[8];
#pragma unroll
    for (int nt = 0; nt < 8; ++nt) {
        b2v[nt] = b2[nt * 16 + n_l];
        w3v[nt] = W3[nt * 16 + n_l];
    }

    f32x4 acc[4][8];
#pragma unroll
    for (int il = 0; il < 4; ++il)
#pragma unroll
        for (int nt = 0; nt < 8; ++nt) acc[il][nt] = f32x4{0.f, 0.f, 0.f, 0.f};

    const bf16x8* wbase = (const bf16x8*)w2f;
    bf16x8 wf[8], wfn[8];
#pragma unroll
    for (int nt = 0; nt < 8; ++nt) wf[nt] = wbase[(nt * 8 + 0) * 64 + l];

    __syncthreads();

#pragma unroll
    for (int ks = 0; ks < 8; ++ks) {
        if (ks < 7) {
#pragma unroll
            for (int nt = 0; nt < 8; ++nt) wfn[nt] = wbase[(nt * 8 + ks + 1) * 64 + l];
        }
#pragma unroll
        for (int il = 0; il < 4; ++il) {
            const int irow = w * 4 + il;
            bf16x8 ha = *(const bf16x8*)(&HaS[irow * 264 + ks * 32 + kq * 8]);
            bf16x8 hb = *(const bf16x8*)(&HbS[n_l * 264 + ks * 32 + kq * 8]);
            bf16x8 av;
#pragma unroll
            for (int e = 0; e < 8; ++e) {
                float v = bf2f((unsigned short)ha[e]) + bf2f((unsigned short)hb[e]);
                v = v > 0.f ? v : 0.f;
                av[e] = (short)f2bf(v);
            }
#pragma unroll
            for (int nt = 0; nt < 8; ++nt)
                acc[il][nt] = __builtin_amdgcn_mfma_f32_16x16x32_bf16(av, wf[nt], acc[il][nt], 0, 0, 0);
        }
#pragma unroll
        for (int nt = 0; nt < 8; ++nt) wf[nt] = wfn[nt];
    }

    // epilogue: h2 relu + dot W3, reduce over n (l&15 butterfly), mask, store
    const float bb3 = b3v[0];
#pragma unroll
    for (int il = 0; il < 4; ++il) {
        float p[4];
#pragma unroll
        for (int reg = 0; reg < 4; ++reg) {
            float v = 0.f;
#pragma unroll
            for (int nt = 0; nt < 8; ++nt) {
                float h2v = acc[il][nt][reg] + b2v[nt];
                h2v = h2v > 0.f ? h2v : 0.f;
                v += h2v * w3v[nt];
            }
            p[reg] = v;
        }
#pragma unroll
        for (int m = 1; m < 16; m <<= 1) {
            p[0] += __shfl_xor(p[0], m);
            p[1] += __shfl_xor(p[1], m);
            p[2] += __shfl_xor(p[2], m);
            p[3] += __shfl_xor(p[3], m);
        }
        if (n_l == 0) {
            const int i = i0 + w * 4 + il;
            const int jb = j0 + kq * 4;
            float4 sv;
            float* pv = &sv.x;
#pragma unroll
            for (int reg = 0; reg < 4; ++reg) {
                int jg = jb + reg;
                float sc = p[reg] + bb3;
                sc = sc > 0.f ? sc : 0.f;
                if (jg == i || jg == 0) sc = 0.f;
                pv[reg] = sc;
            }
            *(float4*)(&score[((size_t)(b * 128 + i)) * 128 + jb]) = sv;
        }
    }
}

// ---------------- loss ----------------
__global__ __launch_bounds__(128) void k_loss1(
    const float* __restrict__ score, const int* __restrict__ tree, float* __restrict__ res)
{
    int k = blockIdx.x;
    int b = blockIdx.y;
    int head = tree[((size_t)b * 128 + k + 1) * 2 + 0];
    int dep  = tree[((size_t)b * 128 + k + 1) * 2 + 1];
    int i = threadIdx.x;
    float s = score[((size_t)b * 128 + i) * 128 + dep];
    float v = (i == dep) ? 0.f : __expf(s);
    __shared__ float redu[2];
#pragma unroll
    for (int off = 32; off >= 1; off >>= 1) v += __shfl_down(v, off, 64);
    if ((i & 63) == 0) redu[i >> 6] = v;
    __syncthreads();
    if (i == 0) {
        float norm = redu[0] + redu[1];
        float num = score[((size_t)b * 128 + head) * 128 + dep];
        res[b * 127 + k] = __logf(norm) - num;
    }
}

__global__ __launch_bounds__(256) void k_loss2(const float* __restrict__ res, float* __restrict__ out) {
    int tid = threadIdx.x;
    float a = 0.f;
    for (int idx = tid; idx < 16 * 127; idx += 256) a += res[idx];
    __shared__ float sm[256];
    sm[tid] = a;
    __syncthreads();
    for (int off = 128; off >= 1; off >>= 1) {
        if (tid < off) sm[tid] += sm[tid + off];
        __syncthreads();
    }
    if (tid == 0) out[0] = sm[0] / 127.f;
}

// ---------------- host launcher ----------------
extern "C" void kernel_launch(void* const* d_in, const int* in_sizes, int n_in,
                              void* d_out, int out_size, void* d_ws, size_t ws_size,
                              hipStream_t stream) {
    (void)in_sizes; (void)n_in; (void)out_size; (void)ws_size;
    const float* X    = (const float*)d_in[0];
    const float* Wih0 = (const float*)d_in[1];
    const float* Whh0 = (const float*)d_in[2];
    const float* bih0 = (const float*)d_in[3];
    const float* bhh0 = (const float*)d_in[4];
    const float* Wih1 = (const float*)d_in[5];
    const float* Whh1 = (const float*)d_in[6];
    const float* bih1 = (const float*)d_in[7];
    const float* bhh1 = (const float*)d_in[8];
    const float* W1   = (const float*)d_in[9];
    const float* b1   = (const float*)d_in[10];
    const float* W2   = (const float*)d_in[11];
    const float* b2   = (const float*)d_in[12];
    const float* W3   = (const float*)d_in[13];
    const float* b3   = (const float*)d_in[14];
    const int*   tree = (const int*)d_in[15];
    float* out = (float*)d_out;   // [0]=loss, [1..]=score

    float* ws = (float*)d_ws;
    size_t o = 0;
    float* WihT0 = ws + o; o += (size_t)2 * 200 * 1024;
    float* WihT1 = ws + o; o += (size_t)2 * 512 * 1024;
    float* W1T   = ws + o; o += (size_t)512 * 512;
    float* bsum0 = ws + o; o += 2048;
    float* bsum1 = ws + o; o += 2048;
    float* bhab  = ws + o; o += 512;
    unsigned short* Wf0 = (unsigned short*)(ws + o); o += (size_t)2 * 16 * 8 * 4 * 64 * 8 / 2;
    unsigned short* Wf1 = (unsigned short*)(ws + o); o += (size_t)2 * 16 * 8 * 4 * 64 * 8 / 2;
    unsigned short* w2f = (unsigned short*)(ws + o); o += (size_t)8 * 8 * 64 * 8 / 2;
    float* xg   = ws + o; o += (size_t)2 * 2048 * 1024;
    float* xgf  = ws + o; o += (size_t)2 * 2048 * 1024;
    unsigned short* embt0 = (unsigned short*)(ws + o); o += (size_t)128 * 512 * 16 / 2;
    unsigned short* embt1 = (unsigned short*)(ws + o); o += (size_t)128 * 512 * 16 / 2;
    float* HaHb = ws + o; o += (size_t)2048 * 512;
    float* res  = ws + o; o += 2048;

    // prep
    k_transpose_N1024<<<dim3(800, 1, 2), 256, 0, stream>>>(Wih0, WihT0, 200);
    k_transpose_N1024<<<dim3(2048, 1, 2), 256, 0, stream>>>(Wih1, WihT1, 512);
    k_wfrag<<<256, 256, 0, stream>>>(Whh0, Wf0);
    k_wfrag<<<256, 256, 0, stream>>>(Whh1, Wf1);
    k_w2frag<<<16, 256, 0, stream>>>(W2, w2f);
    k_w1t<<<1024, 256, 0, stream>>>(W1, W1T);
    k_bias<<<18, 256, 0, stream>>>(bih0, bhh0, bih1, bhh1, b1, bsum0, bsum1, bhab);

    // layer 0
    k_gemm<<<dim3(4, 128, 2), 256, 0, stream>>>(X, WihT0, bsum0, xg, 2048, 200, 1024);
    k_reorder<<<4096, 256, 0, stream>>>(xg, xgf);
    k_lstm_mfma<<<2, 1024, 0, stream>>>(xgf, Wf0, embt0);
    // layer 1
    k_gemm_tl<<<dim3(4, 128, 2), 256, 0, stream>>>(embt0, WihT1, bsum1, xg, 512, 1024);
    k_reorder<<<4096, 256, 0, stream>>>(xg, xgf);
    k_lstm_mfma<<<2, 1024, 0, stream>>>(xgf, Wf1, embt1);
    // Ha|Hb
    k_gemm_tl<<<dim3(2, 128, 1), 256, 0, stream>>>(embt1, W1T, bhab, HaHb, 512, 512);
    // scorer -> out+1
    k_scorer_mfma<<<dim3(8, 8, 16), 256, 0, stream>>>(HaHb, w2f, b2, W3, b3, out + 1);
    // loss
    k_loss1<<<dim3(127, 16), 128, 0, stream>>>(out + 1, tree, res);
    k_loss2<<<1, 256, 0, stream>>>(res, out);
}